// Round 1
// 2152.189 us; speedup vs baseline: 1.5637x; 1.5637x over previous
//
#include <hip/hip_runtime.h>
#include <stdint.h>

typedef __bf16 bf16;
typedef __bf16 bf16x8 __attribute__((ext_vector_type(8)));
typedef float  f32x4  __attribute__((ext_vector_type(4)));

// Problem sizes (fixed): V=8192 E=192 H=512 B=32 T=512 ; BT=16384 ; gate cols N=2048

// ---------------- workspace layout (bytes) ----------------
static constexpr size_t WS_CTR   = 0;                                   // u32 flags[32] (256B slot)
static constexpr size_t WS_HBUF  = 256;                                 // bf16 [2][32][512] double-buffered h
static constexpr size_t WS_WHT   = WS_HBUF + 2*32*512*2;                // bf16 [2048][512]  Wh^T (h-part, n-major)
static constexpr size_t WS_WXT   = WS_WHT + (size_t)2048*512*2;         // bf16 [2048][512]  Wx^T (x-part)
static constexpr size_t WS_WINT  = WS_WXT + (size_t)2048*512*2;         // bf16 [512][192]   W_in^T
static constexpr size_t WS_WHDT  = WS_WINT + (size_t)512*192*2;         // bf16 [8192][512]  W_head^T
static constexpr size_t WS_BIN   = WS_WHDT + (size_t)8192*512*2;        // f32 [512]
static constexpr size_t WS_BG    = WS_BIN + 512*4;                      // f32 [2048] packed gate biases (f,i,g,o)
static constexpr size_t WS_BHD   = WS_BG + 2048*4;                      // f32 [8192]
static constexpr size_t WS_XTB   = WS_BHD + 8192*4;                     // bf16 [16384][512]  x, row = t*32+b
static constexpr size_t WS_XPROJ = WS_XTB + (size_t)16384*512*2;        // bf16 [16384][2048] xproj+bias, row = t*32+b
static constexpr size_t WS_HS    = WS_XPROJ + (size_t)16384*2048*2;     // bf16 [16384][512]  hs, row = b*512+t
                                                                        // (embB bf16[8192][192] aliased at WS_HS:
                                                                        //  dead before hs is first written)
static constexpr size_t WS_END   = WS_HS + (size_t)16384*512*2;         // ~113.5 MB

// ---------------- helpers ----------------
__device__ __forceinline__ void async_copy16(const void* gsrc, void* ldst) {
  // 16B-per-lane global->LDS DMA; LDS dest must be wave-uniform base (+lane*16 implicit)
  __builtin_amdgcn_global_load_lds(
      (const __attribute__((address_space(1))) unsigned int*)gsrc,
      (__attribute__((address_space(3))) unsigned int*)ldst, 16, 0, 0);
}

__device__ __forceinline__ float sigf(float x) { return 1.f/(1.f + __expf(-x)); }
__device__ __forceinline__ float tanhfast(float x) { return 1.f - 2.f/(__expf(2.f*x) + 1.f); }

// ---------------- f32 -> bf16 elementwise cast (emb) ----------------
__global__ __launch_bounds__(256) void cast_f32_bf16(const float* __restrict__ src,
                                                     bf16* __restrict__ dst, int n4) {
  int i = blockIdx.x*256 + threadIdx.x;
  if (i >= n4) return;
  float4 v = *(const float4*)(src + (size_t)i*4);
  union { bf16 h[4]; uint2 u; } o;
  o.h[0] = (bf16)v.x; o.h[1] = (bf16)v.y; o.h[2] = (bf16)v.z; o.h[3] = (bf16)v.w;
  *(uint2*)(dst + (size_t)i*4) = o.u;
}

// ---------------- transpose f32 src -> bf16 dst (64x64 tiles; dims mult of 64) ----------------
__device__ __forceinline__ void transpose_tile64(const float* __restrict__ src,
                                                 bf16* __restrict__ dst,
                                                 int C /*src ld*/, int R /*dst ld*/) {
  __shared__ float tile[64][68];                // pad to break conflicts
  const int tid = threadIdx.x;
  const int rb = blockIdx.y*64, cb = blockIdx.x*64;
  #pragma unroll
  for (int p = 0; p < 4; ++p) {
    int idx = p*256 + tid;
    int r = idx >> 4, c4 = idx & 15;
    *(float4*)&tile[r][c4*4] = *(const float4*)(src + (size_t)(rb + r)*C + cb + c4*4);
  }
  __syncthreads();
  #pragma unroll
  for (int p = 0; p < 2; ++p) {
    int idx = p*256 + tid;
    int c = idx >> 3, r8 = idx & 7;
    union { bf16 h[8]; uint4 v; } o;
    #pragma unroll
    for (int j = 0; j < 8; ++j) o.h[j] = (bf16)tile[r8*8 + j][c];
    *(uint4*)(dst + (size_t)(cb + c)*R + rb + r8*8) = o.v;
  }
}

__global__ __launch_bounds__(256) void transpose_f32_bf16(const float* __restrict__ src,
                                                          bf16* __restrict__ dst, int R, int C) {
  transpose_tile64(src, dst, C, R);             // dst[c][r] = (bf16)src[r][c]
}

// gate pack: blockIdx.z = gate*2 + half; half 0 -> h-rows (0..511) -> WhT, half 1 -> x-rows -> WxT
__global__ __launch_bounds__(256) void pack_gates(const float* Wf, const float* Wi,
                                                  const float* Wg, const float* Wo,
                                                  bf16* WhT, bf16* WxT) {
  const float* srcs[4] = {Wf, Wi, Wg, Wo};
  const int g = blockIdx.z >> 1, half = blockIdx.z & 1;
  transpose_tile64(srcs[g] + (size_t)half*512*512,
                   (half ? WxT : WhT) + (size_t)g*512*512, 512, 512);
}

__global__ __launch_bounds__(256) void pack_bias(const float* bf_, const float* bi_,
                                                 const float* bg_, const float* bo_,
                                                 const float* b_in, const float* b_head,
                                                 float* bgate, float* binf, float* bheadf) {
  int i = blockIdx.x*256 + threadIdx.x;
  if (i < 2048) {
    const float* s[4] = {bf_, bi_, bg_, bo_};
    bgate[i] = s[i >> 9][i & 511];
  } else if (i < 2048 + 512) {
    binf[i - 2048] = b_in[i - 2048];
  } else {
    bheadf[i - 2560] = b_head[i - 2560];
  }
}

// ---------------- GEMM: C[M][N] = alpha*(A[M][K] @ BT[N][K]^T + bias[N]) ----------------
// m97-style: 128x128 tile, BK=64, global_load_lds(16B), xor-swizzled 8-elem granules.
// GATHER=1: A row r is embB[Xmap[(r&31)*512 + (r>>5)]]   (row = t*32+b ordering)
template<int GATHER, typename OutT>
__global__ __launch_bounds__(256) void gemm_bt(
    const bf16* __restrict__ A, const int* __restrict__ Xmap,
    const bf16* __restrict__ BT, const float* __restrict__ bias,
    OutT* __restrict__ Cc, int M, int N, int K, float alpha)
{
  __shared__ bf16 As[128*64];
  __shared__ bf16 Bs[128*64];
  const int tid  = threadIdx.x;
  const int wave = tid >> 6, lane = tid & 63;
  const int quad = lane >> 4, l15 = lane & 15;
  const int wr = wave >> 1, wc = wave & 1;
  const int rbase = blockIdx.y * 128, cbase = blockIdx.x * 128;

  size_t aoff[4], boff[4];
  int lbase[4];
  #pragma unroll
  for (int q = 0; q < 4; ++q) {
    int gidx = (q*4 + wave)*64 + lane;          // granule 0..1023 (128 rows x 8 slots)
    int row  = gidx >> 3;
    int s    = (gidx & 7) ^ (row & 7);          // slot sx holds segment sx^(row&7)
    int arow = rbase + row;
    size_t asel;
    if constexpr (GATHER) asel = (size_t)Xmap[(arow & 31)*512 + (arow >> 5)];
    else                  asel = (size_t)arow;
    aoff[q]  = asel*(size_t)K + (size_t)(s*8);
    boff[q]  = (size_t)(cbase + row)*(size_t)K + (size_t)(s*8);
    lbase[q] = (q*4 + wave)*64*8;               // wave-uniform LDS base (elements)
  }

  f32x4 acc[4][4] = {};

  for (int k0 = 0; k0 < K; k0 += 64) {
    #pragma unroll
    for (int q = 0; q < 4; ++q) async_copy16(A  + aoff[q] + k0, &As[lbase[q]]);
    #pragma unroll
    for (int q = 0; q < 4; ++q) async_copy16(BT + boff[q] + k0, &Bs[lbase[q]]);
    __syncthreads();                            // drains vmcnt before s_barrier
    #pragma unroll
    for (int kk = 0; kk < 2; ++kk) {
      bf16x8 af[4], bfr[4];
      #pragma unroll
      for (int mt = 0; mt < 4; ++mt) {
        int row = wr*64 + mt*16 + l15;
        int sg  = (kk*4 + quad) ^ (row & 7);
        af[mt] = *(const bf16x8*)&As[row*64 + sg*8];
      }
      #pragma unroll
      for (int nt = 0; nt < 4; ++nt) {
        int row = wc*64 + nt*16 + l15;
        int sg  = (kk*4 + quad) ^ (row & 7);
        bfr[nt] = *(const bf16x8*)&Bs[row*64 + sg*8];
      }
      #pragma unroll
      for (int mt = 0; mt < 4; ++mt)
        #pragma unroll
        for (int nt = 0; nt < 4; ++nt)
          acc[mt][nt] = __builtin_amdgcn_mfma_f32_16x16x32_bf16(af[mt], bfr[nt], acc[mt][nt], 0, 0, 0);
    }
    __syncthreads();
  }

  #pragma unroll
  for (int nt = 0; nt < 4; ++nt) {
    int cg = cbase + wc*64 + nt*16 + l15;
    float bv = bias[cg];
    #pragma unroll
    for (int mt = 0; mt < 4; ++mt) {
      #pragma unroll
      for (int rr = 0; rr < 4; ++rr) {
        int rg = rbase + wr*64 + mt*16 + quad*4 + rr;   // C/D: col=lane&15, row=quad*4+reg
        Cc[(size_t)rg*(size_t)N + (size_t)cg] = (OutT)(alpha*(acc[mt][nt][rr] + bv));
      }
    }
  }
}

// ---------------- persistent LSTM scan: 32 WGs, WG j owns units [j*16, j*16+16) ----------------
// h exchange is fence-free: h is written/read with agent-scope RELAXED atomics (sc-flagged,
// bypass the non-coherent L1/per-XCD L2, hit the coherent point directly).  Ordering:
//   writer: h stores -> __syncthreads (drains vmcnt(0) per wave) -> flag store (per-WG, no RMW)
//   reader: spin on 32-flag line (coalesced wave-wide load) -> branch resolves -> h loads
// This removes the per-step buffer_wbl2 (agent-release) and buffer_inv (agent-acquire) that
// dominated the previous version's 5us/step critical path.
__global__ __launch_bounds__(256) void lstm_scan(
    const bf16* __restrict__ WhT, const bf16* __restrict__ xproj,
    bf16* __restrict__ hbuf, bf16* __restrict__ hs,
    unsigned* __restrict__ flags)
{
  __shared__ bf16  hsh[32*512];                 // staged h, [32 rows][64 slots of 8], slot s holds seg s^(row&7)
  __shared__ float gbuf[4*32*16];               // gate exchange (8 KB)
  const int tid  = threadIdx.x;
  const int wave = tid >> 6, lane = tid & 63;   // wave == gate (0=f,1=i,2=g,3=o)
  const int quad = lane >> 4, l15 = lane & 15;
  const int ub   = blockIdx.x * 16;

  // W fragments resident in registers for the whole scan: B[k][n], n = wave*512 + ub + l15
  bf16x8 wfrag[16];
  {
    const bf16* wp = WhT + (size_t)(wave*512 + ub + l15)*512 + quad*8;
    #pragma unroll
    for (int ks = 0; ks < 16; ++ks) wfrag[ks] = *(const bf16x8*)(wp + ks*32);
  }

  // cell-update mapping: thread owns batch bq, units (ub+up, ub+up+1)  -> aligned u32 h I/O
  const int bq = tid >> 3, up = (tid & 7) * 2;
  float creg0 = 0.f, creg1 = 0.f;               // c state in registers

  #pragma unroll 1
  for (int t = 0; t < 512; ++t) {
    // prefetch xproj[t] (independent of h) before the spin: 4 u32 = 8 bf16
    uint xpu[4];
    {
      const uint* xr = (const uint*)xproj + ((size_t)(t*32 + bq)*1024 + ((ub + up) >> 1));
      #pragma unroll
      for (int g = 0; g < 4; ++g) xpu[g] = xr[g*256];   // gate stride 512 bf16 = 256 u32
    }

    f32x4 acc0 = {}, acc1 = {};
    if (t > 0) {
      // spin until all 32 WGs have published h_{t-1}; one coalesced load per poll
      {
        unsigned v;
        do { v = __hip_atomic_load(&flags[lane & 31], __ATOMIC_RELAXED, __HIP_MEMORY_SCOPE_AGENT); }
        while (__any(v < (unsigned)t));
      }
      // gather h_{t-1} (32x512 bf16 = 4096 u64) via coherent loads, stage to LDS xor-swizzled
      const unsigned long long* hread =
          (const unsigned long long*)hbuf + (size_t)((t - 1) & 1) * 4096;
      unsigned long long hv[16];
      #pragma unroll
      for (int q = 0; q < 16; ++q)
        hv[q] = __hip_atomic_load(hread + q*256 + tid, __ATOMIC_RELAXED, __HIP_MEMORY_SCOPE_AGENT);
      #pragma unroll
      for (int q = 0; q < 16; ++q) {
        int gidx = q*256 + tid;                 // u64 granule; row m, u64-in-row j
        int m = gidx >> 7, j = gidx & 127;
        *(unsigned long long*)&hsh[m*512 + (((j >> 1) ^ (m & 7)) << 3) + ((j & 1) << 2)] = hv[q];
      }
      __syncthreads();
      #pragma unroll
      for (int ks = 0; ks < 16; ++ks) {
        int sg = (ks*4 + quad) ^ (l15 & 7);     // ((16+l15)&7) == (l15&7)
        bf16x8 a0 = *(const bf16x8*)&hsh[(size_t)l15*512      + sg*8];
        bf16x8 a1 = *(const bf16x8*)&hsh[(size_t)(16+l15)*512 + sg*8];
        acc0 = __builtin_amdgcn_mfma_f32_16x16x32_bf16(a0, wfrag[ks], acc0, 0, 0, 0);
        acc1 = __builtin_amdgcn_mfma_f32_16x16x32_bf16(a1, wfrag[ks], acc1, 0, 0, 0);
      }
    }
    // exchange gate preacts (h-part): D[row=batch][col=unit], row=quad*4+rr, col=l15
    {
      float* gb = &gbuf[wave*512];
      #pragma unroll
      for (int rr = 0; rr < 4; ++rr) {
        gb[(quad*4 + rr)*16 + l15]      = acc0[rr];
        gb[(16 + quad*4 + rr)*16 + l15] = acc1[rr];
      }
    }
    __syncthreads();
    // elementwise cell update; gbuf index = g*512 + b*16 + u  (u = up, up+1 contiguous)
    {
      float2 gf = *(const float2*)&gbuf[       bq*16 + up];
      float2 gi = *(const float2*)&gbuf[512  + bq*16 + up];
      float2 gg = *(const float2*)&gbuf[1024 + bq*16 + up];
      float2 go = *(const float2*)&gbuf[1536 + bq*16 + up];
      union U { uint u; bf16 h[2]; };
      U xf{xpu[0]}, xi{xpu[1]}, xg{xpu[2]}, xo{xpu[3]};
      float pf0 = gf.x + (float)xf.h[0], pf1 = gf.y + (float)xf.h[1];
      float pi0 = gi.x + (float)xi.h[0], pi1 = gi.y + (float)xi.h[1];
      float pg0 = gg.x + (float)xg.h[0], pg1 = gg.y + (float)xg.h[1];
      float po0 = go.x + (float)xo.h[0], po1 = go.y + (float)xo.h[1];

      creg0 = creg0*sigf(pf0) + sigf(pi0)*tanhfast(pg0);
      creg1 = creg1*sigf(pf1) + sigf(pi1)*tanhfast(pg1);
      U hh;
      hh.h[0] = (bf16)(tanhfast(creg0)*sigf(po0));
      hh.h[1] = (bf16)(tanhfast(creg1)*sigf(po1));

      // publish h (agent-coherent, no fence needed)
      uint* hw = (uint*)hbuf + ((size_t)(t & 1)*8192 + bq*256 + ((ub + up) >> 1));
      __hip_atomic_store(hw, hh.u, __ATOMIC_RELAXED, __HIP_MEMORY_SCOPE_AGENT);
      // hs (plain cached store; consumed after kernel end)
      *((uint*)hs + ((size_t)bq*512 + t)*256 + ((ub + up) >> 1)) = hh.u;
    }
    __syncthreads();                            // all waves' stores drained (vmcnt 0) before publish
    if (tid == 0)
      __hip_atomic_store(&flags[blockIdx.x], (unsigned)(t + 1),
                         __ATOMIC_RELAXED, __HIP_MEMORY_SCOPE_AGENT);
  }
}

// ---------------- launch ----------------
extern "C" void kernel_launch(void* const* d_in, const int* in_sizes, int n_in,
                              void* d_out, int out_size, void* d_ws, size_t ws_size,
                              hipStream_t stream) {
  (void)in_sizes; (void)n_in; (void)out_size;
  if (ws_size < WS_END) return;                 // visible failure (absmax = max|ref|) if ws too small

  const int*   X    = (const int*)  d_in[0];
  const float* emb  = (const float*)d_in[1];
  const float* W_in = (const float*)d_in[2];
  const float* b_in = (const float*)d_in[3];
  const float* Wf   = (const float*)d_in[4];
  const float* bfv  = (const float*)d_in[5];
  const float* Wi   = (const float*)d_in[6];
  const float* biv  = (const float*)d_in[7];
  const float* Wg   = (const float*)d_in[8];
  const float* bgv  = (const float*)d_in[9];
  const float* Wo   = (const float*)d_in[10];
  const float* bov  = (const float*)d_in[11];
  const float* Whd  = (const float*)d_in[12];
  const float* bhd  = (const float*)d_in[13];

  char* ws = (char*)d_ws;
  unsigned* flags = (unsigned*)(ws + WS_CTR);
  bf16*  hbuf   = (bf16*)(ws + WS_HBUF);
  bf16*  WhT    = (bf16*)(ws + WS_WHT);
  bf16*  WxT    = (bf16*)(ws + WS_WXT);
  bf16*  WinT   = (bf16*)(ws + WS_WINT);
  bf16*  WhdT   = (bf16*)(ws + WS_WHDT);
  float* binf   = (float*)(ws + WS_BIN);
  float* bgate  = (float*)(ws + WS_BG);
  float* bheadf = (float*)(ws + WS_BHD);
  bf16*  x_tb   = (bf16*)(ws + WS_XTB);
  bf16*  xproj  = (bf16*)(ws + WS_XPROJ);
  bf16*  hs     = (bf16*)(ws + WS_HS);
  bf16*  embB   = (bf16*)(ws + WS_HS);          // alias: embB dead before hs first written

  hipMemsetAsync(ws + WS_CTR, 0, 256, stream);

  cast_f32_bf16<<<dim3((8192*192/4 + 255)/256), 256, 0, stream>>>(emb, embB, 8192*192/4);
  pack_gates<<<dim3(8, 8, 8), 256, 0, stream>>>(Wf, Wi, Wg, Wo, WhT, WxT);
  transpose_f32_bf16<<<dim3(8192/64, 512/64), 256, 0, stream>>>(Whd, WhdT, 512, 8192);
  transpose_f32_bf16<<<dim3(512/64, 192/64), 256, 0, stream>>>(W_in, WinT, 192, 512);
  pack_bias<<<dim3(42), 256, 0, stream>>>(bfv, biv, bgv, bov, b_in, bhd, bgate, binf, bheadf);

  // x[t*32+b][512] = embB[X[b][t]] @ W_in + b_in
  gemm_bt<1, bf16><<<dim3(512/128, 16384/128), 256, 0, stream>>>(
      embB, X, WinT, binf, x_tb, 16384, 512, 192, 1.0f);
  // xproj[t*32+b][2048] = x @ Wx + b_gates   (gate-major cols: f,i,g,o)
  gemm_bt<0, bf16><<<dim3(2048/128, 16384/128), 256, 0, stream>>>(
      x_tb, nullptr, WxT, bgate, xproj, 16384, 2048, 512, 1.0f);
  // sequential scan -> hs[b*512+t][512]
  lstm_scan<<<dim3(32), 256, 0, stream>>>(WhT, xproj, hbuf, hs, flags);
  // logits[b*512+t][8192] = 0.1*(hs @ W_head + b_head), f32 out
  gemm_bt<0, float><<<dim3(8192/128, 16384/128), 256, 0, stream>>>(
      hs, nullptr, WhdT, bheadf, (float*)d_out, 16384, 8192, 512, 0.1f);
}